// Round 4
// baseline (8783.683 us; speedup 1.0000x reference)
//
#include <hip/hip_runtime.h>
#include <stdint.h>
#include <stddef.h>

// GRU (B=32, T=2048, I=H=512, fp32 in/out), fully fused persistent scan.
// 256 WGs = 32 batches x 8 slices. Cross-WG exchange is SELF-SYNCHRONIZING:
// every exchanged scalar is an atomic u64 { tag=step+1 : f32 bits }; readers
// spin on the datum's tag. Double-buffered by step parity.
// R4 change: __launch_bounds__(512, 2) -> VGPR cap 256 (was 128), so the 192
// packed-fp16 weight registers stay RESIDENT across the 2048-step loop
// instead of being rematerialized (re-loaded + re-converted) every step.
// 1 WG/CU either way, so no occupancy loss.

#define AGENT __HIP_MEMORY_SCOPE_AGENT

typedef _Float16 h2v __attribute__((ext_vector_type(2)));

__device__ __forceinline__ h2v pk2(float a, float b) {
  h2v r; r[0] = (_Float16)a; r[1] = (_Float16)b; return r;
}
__device__ __forceinline__ float dot2f(h2v a, h2v b, float c) {
#if __has_builtin(__builtin_amdgcn_fdot2)
  return __builtin_amdgcn_fdot2(a, b, c, false);
#else
  return fmaf((float)a[1], (float)b[1], fmaf((float)a[0], (float)b[0], c));
#endif
}
__device__ __forceinline__ h2v bc2(uint32_t u) { return __builtin_bit_cast(h2v, u); }

__device__ __forceinline__ float sigmoidf_(float x) { return 1.0f / (1.0f + __expf(-x)); }
__device__ __forceinline__ float tanhf_(float x) { return 1.0f - 2.0f / (1.0f + __expf(2.0f * x)); }

__device__ __forceinline__ uint64_t ald64(const uint64_t* p) {
  return __hip_atomic_load(p, __ATOMIC_RELAXED, AGENT);
}
__device__ __forceinline__ void ast64(uint64_t* p, uint64_t v) {
  __hip_atomic_store(p, v, __ATOMIC_RELAXED, AGENT);
}

__global__ __launch_bounds__(512, 2) void gru_fused_kernel(
    const float* __restrict__ x,     // [32][2048][512]
    const float* __restrict__ Wx,    // [3][512][512]
    const float* __restrict__ Wh,    // [3][512][512]
    const float* __restrict__ bias,  // [3][512]
    float* __restrict__ out,         // [32][2048][512] then [32][512]
    uint64_t* __restrict__ Pbuf,     // [2][32][8][512] tagged
    uint64_t* __restrict__ zbuf) {   // [2][32][512] tagged
  __shared__ _Float16 h16[512];   // h_{t-1} (fp16 GEMV operand)
  __shared__ _Float16 x16[512];   // x_t
  __shared__ _Float16 rh16[64];   // (r*h) for this WG's column slice

  const int T = threadIdx.x;
  const int bid = blockIdx.x;
  const int xcd = bid & 7, ii = bid >> 3;
  const int batch = xcd * 4 + (ii >> 3);  // 8 WGs of a batch share an XCD (heuristic only)
  const int slice = ii & 7;
  const int c = T >> 3, s = T & 7;  // column-in-slice, K-octant
  const int jg = slice * 64 + c;    // this thread's z/r output column

  // ---- resident weights: packed fp16 pairs, fully unrolled static indexing ----
  h2v wz2[64], wr2[64], wh2[64];
  {
    const float* Whz = Wh;
    const float* Whr = Wh + 262144;
    const float* Wxz = Wx;
    const float* Wxr = Wx + 262144;
#pragma unroll
    for (int j = 0; j < 16; ++j) {
      int p = (j + 2 * s) & 15;  // bank rotation for conflict-free ds_read_b64
      int k = s * 64 + 4 * p;
#pragma unroll
      for (int q = 0; q < 2; ++q) {
        int kk = k + 2 * q;
        wz2[2 * j + q]      = pk2(Whz[(size_t)kk * 512 + jg], Whz[(size_t)(kk + 1) * 512 + jg]);
        wr2[2 * j + q]      = pk2(Whr[(size_t)kk * 512 + jg], Whr[(size_t)(kk + 1) * 512 + jg]);
        wz2[32 + 2 * j + q] = pk2(Wxz[(size_t)kk * 512 + jg], Wxz[(size_t)(kk + 1) * 512 + jg]);
        wr2[32 + 2 * j + q] = pk2(Wxr[(size_t)kk * 512 + jg], Wxr[(size_t)(kk + 1) * 512 + jg]);
      }
    }
    const float* Whh = Wh + 524288;
    const float* Wxh = Wx + 524288;
#pragma unroll
    for (int j = 0; j < 16; ++j) {
      int k = slice * 64 + 4 * j;
#pragma unroll
      for (int q = 0; q < 2; ++q) {
        int kk = k + 2 * q;
        wh2[2 * j + q]      = pk2(Whh[(size_t)kk * 512 + T], Whh[(size_t)(kk + 1) * 512 + T]);
        wh2[32 + 2 * j + q] = pk2(Wxh[(size_t)kk * 512 + T], Wxh[(size_t)(kk + 1) * 512 + T]);
      }
    }
  }
  const float bz = bias[jg], br = bias[512 + jg], bh = bias[1024 + T];

  float hreg = 0.0f;
  h16[T] = (_Float16)0.0f;
  float x_p = x[((size_t)batch * 2048) * 512 + T];  // prefetch x row 0

  uint64_t* Pmine = Pbuf + ((size_t)batch * 8 + slice) * 512 + T;   // + pp*131072
  const uint64_t* Pread = Pbuf + ((size_t)batch * 8) * 512 + T;
  uint64_t* zmine = zbuf + (size_t)batch * 512 + jg;                 // + pp*16384
  const uint64_t* zread = zbuf + (size_t)batch * 512 + T;

  for (int t = 0; t < 2048; ++t) {
    if (t > 0) {
      // combine step t-1: spin-gather 8 tagged partials + tagged z
      const size_t po = ((t - 1) & 1) ? 131072 : 0;
      const size_t zo = ((t - 1) & 1) ? 16384 : 0;
      const uint32_t want = (uint32_t)t;  // tag = producing step + 1
      uint64_t v[8];
#pragma unroll
      for (int g = 0; g < 8; ++g) v[g] = ald64(Pread + po + (size_t)g * 512);
      uint64_t zv = ald64(zread + zo);
      for (;;) {
        bool ok = true;
        if ((uint32_t)(zv >> 32) != want) { zv = ald64(zread + zo); ok = false; }
#pragma unroll
        for (int g = 0; g < 8; ++g)
          if ((uint32_t)(v[g] >> 32) != want) { v[g] = ald64(Pread + po + (size_t)g * 512); ok = false; }
        if (ok) break;
        __builtin_amdgcn_s_sleep(1);
      }
      float hsum = 0.f;
#pragma unroll
      for (int g = 0; g < 8; ++g) hsum += __uint_as_float((uint32_t)v[g]);
      float zf = __uint_as_float((uint32_t)zv);
      float htil = tanhf_(bh + hsum);
      float hn = fmaf(zf, htil - hreg, hreg);
      if (slice == 0) out[((size_t)batch * 2048 + (t - 1)) * 512 + T] = hn;
      hreg = hn;
      h16[T] = (_Float16)hn;
    }
    x16[T] = (_Float16)x_p;
    __syncthreads();  // B1: h16/x16 visible WG-wide
    if (t < 2047) x_p = x[((size_t)batch * 2048 + t + 1) * 512 + T];

    // ---- z/r GEMV: K=1024 (512 h rows + 512 x rows), per-octant ----
    float za = 0.f, ra = 0.f;
#pragma unroll
    for (int j = 0; j < 16; ++j) {
      int p = (j + 2 * s) & 15;
      int k = s * 64 + 4 * p;
      uint2 hu = *(const uint2*)&h16[k];
      uint2 xu = *(const uint2*)&x16[k];
      za = dot2f(bc2(hu.x), wz2[2 * j], za);
      za = dot2f(bc2(hu.y), wz2[2 * j + 1], za);
      ra = dot2f(bc2(hu.x), wr2[2 * j], ra);
      ra = dot2f(bc2(hu.y), wr2[2 * j + 1], ra);
      za = dot2f(bc2(xu.x), wz2[32 + 2 * j], za);
      za = dot2f(bc2(xu.y), wz2[33 + 2 * j], za);
      ra = dot2f(bc2(xu.x), wr2[32 + 2 * j], ra);
      ra = dot2f(bc2(xu.y), wr2[33 + 2 * j], ra);
    }
#pragma unroll
    for (int d = 1; d < 8; d <<= 1) { za += __shfl_xor(za, d); ra += __shfl_xor(ra, d); }
    const size_t po = (t & 1) ? 131072 : 0;
    const size_t zo = (t & 1) ? 16384 : 0;
    const uint64_t tagw = ((uint64_t)(uint32_t)(t + 1)) << 32;
    float z = sigmoidf_(za + bz);
    float r = sigmoidf_(ra + br);
    if (s == 0) {
      rh16[c] = (_Float16)(r * (float)h16[jg]);
      ast64(zmine + zo, tagw | (uint32_t)__float_as_uint(z));
    }
    __syncthreads();  // B2: rh16 visible

    // ---- split-K candidate partial: P[n] = rh_slice @ W_hh + x_slice @ W_xh ----
    float pa = 0.f;
#pragma unroll
    for (int j = 0; j < 16; ++j) {
      uint2 ru = *(const uint2*)&rh16[4 * j];              // uniform -> LDS broadcast
      uint2 xu = *(const uint2*)&x16[slice * 64 + 4 * j];  // uniform -> LDS broadcast
      pa = dot2f(bc2(ru.x), wh2[2 * j], pa);
      pa = dot2f(bc2(ru.y), wh2[2 * j + 1], pa);
      pa = dot2f(bc2(xu.x), wh2[32 + 2 * j], pa);
      pa = dot2f(bc2(xu.y), wh2[33 + 2 * j], pa);
    }
    ast64(Pmine + po, tagw | (uint32_t)__float_as_uint(pa));
    __syncthreads();  // B3: t's LDS reads done before next iter's h16/x16/rh16 writes
  }

  // epilogue: finalize step 2047 (parity 1, tag 2048) -> out row 2047 + h_last
  {
    const uint32_t want = 2048u;
    uint64_t v[8];
#pragma unroll
    for (int g = 0; g < 8; ++g) v[g] = ald64(Pread + 131072 + (size_t)g * 512);
    uint64_t zv = ald64(zread + 16384);
    for (;;) {
      bool ok = true;
      if ((uint32_t)(zv >> 32) != want) { zv = ald64(zread + 16384); ok = false; }
#pragma unroll
      for (int g = 0; g < 8; ++g)
        if ((uint32_t)(v[g] >> 32) != want) { v[g] = ald64(Pread + 131072 + (size_t)g * 512); ok = false; }
      if (ok) break;
      __builtin_amdgcn_s_sleep(1);
    }
    float hsum = 0.f;
#pragma unroll
    for (int g = 0; g < 8; ++g) hsum += __uint_as_float((uint32_t)v[g]);
    float zf = __uint_as_float((uint32_t)zv);
    float htil = tanhf_(bh + hsum);
    float hn = fmaf(zf, htil - hreg, hreg);
    if (slice == 0) {
      out[((size_t)batch * 2048 + 2047) * 512 + T] = hn;
      out[(size_t)32 * 2048 * 512 + (size_t)batch * 512 + T] = hn;
    }
  }
}

extern "C" void kernel_launch(void* const* d_in, const int* in_sizes, int n_in,
                              void* d_out, int out_size, void* d_ws, size_t ws_size,
                              hipStream_t stream) {
  (void)in_sizes; (void)n_in; (void)out_size; (void)ws_size;
  const float* x    = (const float*)d_in[0];
  const float* Wx   = (const float*)d_in[1];
  const float* Wh   = (const float*)d_in[2];
  const float* bias = (const float*)d_in[3];
  float* out = (float*)d_out;
  char* ws = (char*)d_ws;

  uint64_t* Pbuf = (uint64_t*)ws;                  // 2*32*8*512*8 = 2,097,152 B
  uint64_t* zbuf = (uint64_t*)(ws + 2097152);      // 2*32*512*8  =   524,288 B

  // zero tags every call (graph-captured, replay-safe; kills stale-tag collisions)
  hipMemsetAsync(ws, 0, 2621440, stream);
  gru_fused_kernel<<<256, 512, 0, stream>>>(x, Wx, Wh, bias, out, Pbuf, zbuf);
}

// Round 5
// 8630.927 us; speedup vs baseline: 1.0177x; 1.0177x over previous
//
#include <hip/hip_runtime.h>
#include <stdint.h>
#include <stddef.h>

// GRU (B=32, T=2048, I=H=512, fp32 in/out), fully fused persistent scan.
// 256 WGs = 32 batches x 8 slices. Cross-WG exchange is SELF-SYNCHRONIZING:
// every exchanged scalar is an atomic u64 { tag=step+1 : f32 bits }; readers
// spin on the datum's tag. Double-buffered by step parity.
// R5 change: weight values are forced RESIDENT via an opaque asm barrier
// (asm volatile "+v") after init. R4 showed VGPR_Count stuck at 128 with
// identical timing: the allocator rematerialized the pure load->cvt->pack
// chains every step (L1-BW bound, ~786KB/WG/step). The asm def makes remat
// illegal, so the 192 packed-fp16 weight words stay in VGPRs for all 2048
// steps. launch_bounds(512,2) provides the 256-VGPR budget; 1 WG/CU.

#define AGENT __HIP_MEMORY_SCOPE_AGENT

typedef _Float16 h2v __attribute__((ext_vector_type(2)));

__device__ __forceinline__ uint32_t pk2u(float a, float b) {
  h2v r; r[0] = (_Float16)a; r[1] = (_Float16)b;
  return __builtin_bit_cast(uint32_t, r);
}
__device__ __forceinline__ h2v bc2(uint32_t u) { return __builtin_bit_cast(h2v, u); }
__device__ __forceinline__ float dot2f(h2v a, h2v b, float c) {
#if __has_builtin(__builtin_amdgcn_fdot2)
  return __builtin_amdgcn_fdot2(a, b, c, false);
#else
  return fmaf((float)a[1], (float)b[1], fmaf((float)a[0], (float)b[0], c));
#endif
}

__device__ __forceinline__ float sigmoidf_(float x) { return 1.0f / (1.0f + __expf(-x)); }
__device__ __forceinline__ float tanhf_(float x) { return 1.0f - 2.0f / (1.0f + __expf(2.0f * x)); }

__device__ __forceinline__ uint64_t ald64(const uint64_t* p) {
  return __hip_atomic_load(p, __ATOMIC_RELAXED, AGENT);
}
__device__ __forceinline__ void ast64(uint64_t* p, uint64_t v) {
  __hip_atomic_store(p, v, __ATOMIC_RELAXED, AGENT);
}

__global__ __launch_bounds__(512, 2) void gru_fused_kernel(
    const float* __restrict__ x,     // [32][2048][512]
    const float* __restrict__ Wx,    // [3][512][512]
    const float* __restrict__ Wh,    // [3][512][512]
    const float* __restrict__ bias,  // [3][512]
    float* __restrict__ out,         // [32][2048][512] then [32][512]
    uint64_t* __restrict__ Pbuf,     // [2][32][8][512] tagged
    uint64_t* __restrict__ zbuf) {   // [2][32][512] tagged
  __shared__ _Float16 h16[512];   // h_{t-1} (fp16 GEMV operand)
  __shared__ _Float16 x16[512];   // x_t
  __shared__ _Float16 rh16[64];   // (r*h) for this WG's column slice

  const int T = threadIdx.x;
  const int bid = blockIdx.x;
  const int xcd = bid & 7, ii = bid >> 3;
  const int batch = xcd * 4 + (ii >> 3);  // 8 WGs of a batch share an XCD (heuristic only)
  const int slice = ii & 7;
  const int c = T >> 3, s = T & 7;  // column-in-slice, K-octant
  const int jg = slice * 64 + c;    // this thread's z/r output column

  // ---- resident weights: packed fp16 pairs as raw u32 words ----
  uint32_t wz2[64], wr2[64], wh2[64];
  {
    const float* Whz = Wh;
    const float* Whr = Wh + 262144;
    const float* Wxz = Wx;
    const float* Wxr = Wx + 262144;
#pragma unroll
    for (int j = 0; j < 16; ++j) {
      int p = (j + 2 * s) & 15;  // bank rotation for conflict-free ds_read_b64
      int k = s * 64 + 4 * p;
#pragma unroll
      for (int q = 0; q < 2; ++q) {
        int kk = k + 2 * q;
        wz2[2 * j + q]      = pk2u(Whz[(size_t)kk * 512 + jg], Whz[(size_t)(kk + 1) * 512 + jg]);
        wr2[2 * j + q]      = pk2u(Whr[(size_t)kk * 512 + jg], Whr[(size_t)(kk + 1) * 512 + jg]);
        wz2[32 + 2 * j + q] = pk2u(Wxz[(size_t)kk * 512 + jg], Wxz[(size_t)(kk + 1) * 512 + jg]);
        wr2[32 + 2 * j + q] = pk2u(Wxr[(size_t)kk * 512 + jg], Wxr[(size_t)(kk + 1) * 512 + jg]);
      }
    }
    const float* Whh = Wh + 524288;
    const float* Wxh = Wx + 524288;
#pragma unroll
    for (int j = 0; j < 16; ++j) {
      int k = slice * 64 + 4 * j;
#pragma unroll
      for (int q = 0; q < 2; ++q) {
        int kk = k + 2 * q;
        wh2[2 * j + q]      = pk2u(Whh[(size_t)kk * 512 + T], Whh[(size_t)(kk + 1) * 512 + T]);
        wh2[32 + 2 * j + q] = pk2u(Wxh[(size_t)kk * 512 + T], Wxh[(size_t)(kk + 1) * 512 + T]);
      }
    }
  }
  // Opaque def: forbid rematerialization / scratch-parking of the weight words.
#pragma unroll
  for (int i = 0; i < 64; ++i) {
    asm volatile("" : "+v"(wz2[i]));
    asm volatile("" : "+v"(wr2[i]));
    asm volatile("" : "+v"(wh2[i]));
  }
  const float bz = bias[jg], br = bias[512 + jg], bh = bias[1024 + T];

  float hreg = 0.0f;
  h16[T] = (_Float16)0.0f;
  float x_p = x[((size_t)batch * 2048) * 512 + T];  // prefetch x row 0

  uint64_t* Pmine = Pbuf + ((size_t)batch * 8 + slice) * 512 + T;   // + pp*131072
  const uint64_t* Pread = Pbuf + ((size_t)batch * 8) * 512 + T;
  uint64_t* zmine = zbuf + (size_t)batch * 512 + jg;                 // + pp*16384
  const uint64_t* zread = zbuf + (size_t)batch * 512 + T;

  for (int t = 0; t < 2048; ++t) {
    if (t > 0) {
      // combine step t-1: spin-gather 8 tagged partials + tagged z
      const size_t po = ((t - 1) & 1) ? 131072 : 0;
      const size_t zo = ((t - 1) & 1) ? 16384 : 0;
      const uint32_t want = (uint32_t)t;  // tag = producing step + 1
      uint64_t v[8];
#pragma unroll
      for (int g = 0; g < 8; ++g) v[g] = ald64(Pread + po + (size_t)g * 512);
      uint64_t zv = ald64(zread + zo);
      for (;;) {
        bool ok = true;
        if ((uint32_t)(zv >> 32) != want) { zv = ald64(zread + zo); ok = false; }
#pragma unroll
        for (int g = 0; g < 8; ++g)
          if ((uint32_t)(v[g] >> 32) != want) { v[g] = ald64(Pread + po + (size_t)g * 512); ok = false; }
        if (ok) break;
        __builtin_amdgcn_s_sleep(1);
      }
      float hsum = 0.f;
#pragma unroll
      for (int g = 0; g < 8; ++g) hsum += __uint_as_float((uint32_t)v[g]);
      float zf = __uint_as_float((uint32_t)zv);
      float htil = tanhf_(bh + hsum);
      float hn = fmaf(zf, htil - hreg, hreg);
      if (slice == 0) out[((size_t)batch * 2048 + (t - 1)) * 512 + T] = hn;
      hreg = hn;
      h16[T] = (_Float16)hn;
    }
    x16[T] = (_Float16)x_p;
    __syncthreads();  // B1: h16/x16 visible WG-wide
    if (t < 2047) x_p = x[((size_t)batch * 2048 + t + 1) * 512 + T];

    // ---- z/r GEMV: K=1024 (512 h rows + 512 x rows), per-octant ----
    float za = 0.f, ra = 0.f;
#pragma unroll
    for (int j = 0; j < 16; ++j) {
      int p = (j + 2 * s) & 15;
      int k = s * 64 + 4 * p;
      uint2 hu = *(const uint2*)&h16[k];
      uint2 xu = *(const uint2*)&x16[k];
      za = dot2f(bc2(hu.x), bc2(wz2[2 * j]), za);
      za = dot2f(bc2(hu.y), bc2(wz2[2 * j + 1]), za);
      ra = dot2f(bc2(hu.x), bc2(wr2[2 * j]), ra);
      ra = dot2f(bc2(hu.y), bc2(wr2[2 * j + 1]), ra);
      za = dot2f(bc2(xu.x), bc2(wz2[32 + 2 * j]), za);
      za = dot2f(bc2(xu.y), bc2(wz2[33 + 2 * j]), za);
      ra = dot2f(bc2(xu.x), bc2(wr2[32 + 2 * j]), ra);
      ra = dot2f(bc2(xu.y), bc2(wr2[33 + 2 * j]), ra);
    }
#pragma unroll
    for (int d = 1; d < 8; d <<= 1) { za += __shfl_xor(za, d); ra += __shfl_xor(ra, d); }
    const size_t po = (t & 1) ? 131072 : 0;
    const size_t zo = (t & 1) ? 16384 : 0;
    const uint64_t tagw = ((uint64_t)(uint32_t)(t + 1)) << 32;
    float z = sigmoidf_(za + bz);
    float r = sigmoidf_(ra + br);
    if (s == 0) {
      rh16[c] = (_Float16)(r * (float)h16[jg]);
      ast64(zmine + zo, tagw | (uint32_t)__float_as_uint(z));
    }
    __syncthreads();  // B2: rh16 visible

    // ---- split-K candidate partial: P[n] = rh_slice @ W_hh + x_slice @ W_xh ----
    float pa = 0.f;
#pragma unroll
    for (int j = 0; j < 16; ++j) {
      uint2 ru = *(const uint2*)&rh16[4 * j];              // uniform -> LDS broadcast
      uint2 xu = *(const uint2*)&x16[slice * 64 + 4 * j];  // uniform -> LDS broadcast
      pa = dot2f(bc2(ru.x), bc2(wh2[2 * j]), pa);
      pa = dot2f(bc2(ru.y), bc2(wh2[2 * j + 1]), pa);
      pa = dot2f(bc2(xu.x), bc2(wh2[32 + 2 * j]), pa);
      pa = dot2f(bc2(xu.y), bc2(wh2[33 + 2 * j]), pa);
    }
    ast64(Pmine + po, tagw | (uint32_t)__float_as_uint(pa));
    __syncthreads();  // B3: t's LDS reads done before next iter's h16/x16/rh16 writes
  }

  // epilogue: finalize step 2047 (parity 1, tag 2048) -> out row 2047 + h_last
  {
    const uint32_t want = 2048u;
    uint64_t v[8];
#pragma unroll
    for (int g = 0; g < 8; ++g) v[g] = ald64(Pread + 131072 + (size_t)g * 512);
    uint64_t zv = ald64(zread + 16384);
    for (;;) {
      bool ok = true;
      if ((uint32_t)(zv >> 32) != want) { zv = ald64(zread + 16384); ok = false; }
#pragma unroll
      for (int g = 0; g < 8; ++g)
        if ((uint32_t)(v[g] >> 32) != want) { v[g] = ald64(Pread + 131072 + (size_t)g * 512); ok = false; }
      if (ok) break;
      __builtin_amdgcn_s_sleep(1);
    }
    float hsum = 0.f;
#pragma unroll
    for (int g = 0; g < 8; ++g) hsum += __uint_as_float((uint32_t)v[g]);
    float zf = __uint_as_float((uint32_t)zv);
    float htil = tanhf_(bh + hsum);
    float hn = fmaf(zf, htil - hreg, hreg);
    if (slice == 0) {
      out[((size_t)batch * 2048 + 2047) * 512 + T] = hn;
      out[(size_t)32 * 2048 * 512 + (size_t)batch * 512 + T] = hn;
    }
  }
}

extern "C" void kernel_launch(void* const* d_in, const int* in_sizes, int n_in,
                              void* d_out, int out_size, void* d_ws, size_t ws_size,
                              hipStream_t stream) {
  (void)in_sizes; (void)n_in; (void)out_size; (void)ws_size;
  const float* x    = (const float*)d_in[0];
  const float* Wx   = (const float*)d_in[1];
  const float* Wh   = (const float*)d_in[2];
  const float* bias = (const float*)d_in[3];
  float* out = (float*)d_out;
  char* ws = (char*)d_ws;

  uint64_t* Pbuf = (uint64_t*)ws;                  // 2*32*8*512*8 = 2,097,152 B
  uint64_t* zbuf = (uint64_t*)(ws + 2097152);      // 2*32*512*8  =   524,288 B

  // zero tags every call (graph-captured, replay-safe; kills stale-tag collisions)
  hipMemsetAsync(ws, 0, 2621440, stream);
  gru_fused_kernel<<<256, 512, 0, stream>>>(x, Wx, Wh, bias, out, Pbuf, zbuf);
}